// Round 14
// baseline (213.899 us; speedup 1.0000x reference)
//
#include <hip/hip_runtime.h>

#define EPS 1e-3f

// ---------------- workspace layout (float slots) ----------------
// bytes 0..28671 : bf16 fused weights (init_k blk 0)
//   w1B   u16[4 t][64 lane][8]        @ u16 0     (4KB)  B-frag: B[k][ch=t*16+c]
//   w2aA  u16[8 mt][64 lane][8]       @ u16 2048  (8KB)  A-frag: A[hch=mt*16+c][k]
//   w2bB  u16[16 f=ks*4+t][64 ln][8]  @ u16 6144  (16KB) B-frag: B[k=ks*32+..][ch=t*16+c]
#define OFF_T2B    7168              // f32[64]
#define OFF_MPP    7232              // f32[64][64] max-pool partials (memset)
#define OFF_CNT    11392             // i32[20016]  histogram (memset w/ mpp)
#define OFF_OFFS   31408             // i32[S+1] CSR offsets
#define OFF_CUR    51424             // i32[S]   scatter cursors
#define OFF_INPS   71424             // bf16[N][16] sorted inputs (32B/pt)

typedef short short8 __attribute__((ext_vector_type(8)));
typedef float f32x4 __attribute__((ext_vector_type(4)));

union U4 { unsigned u[4]; short8 s8; uint4 u4; };

__device__ inline unsigned short f2bf(float f) {           // RNE f32->bf16
    unsigned u = __float_as_uint(f);
    return (unsigned short)((u + 0x7FFFu + ((u >> 16) & 1u)) >> 16);
}

// block 0: fuse BN into bf16 weights; blocks 1..: histogram of unq
__global__ __launch_bounds__(256) void init_k(
    const float* __restrict__ W1,
    const float* __restrict__ g1, const float* __restrict__ b1,
    const float* __restrict__ m1, const float* __restrict__ v1,
    const float* __restrict__ W2a,
    const float* __restrict__ g2a, const float* __restrict__ b2a,
    const float* __restrict__ m2a, const float* __restrict__ v2a,
    const float* __restrict__ W2b,
    const float* __restrict__ g2b, const float* __restrict__ b2b,
    const float* __restrict__ m2b, const float* __restrict__ v2b,
    unsigned short* __restrict__ wsu, float* __restrict__ wsf,
    const int* __restrict__ unq, int* __restrict__ cnt, int N)
{
    const int t = threadIdx.x;
    if (blockIdx.x == 0) {
        for (int i = t; i < 2048; i += 256) {           // w1B (B-frag)
            int tt = i >> 9, lane = (i >> 3) & 63, j = i & 7;
            int c = lane & 15, g = lane >> 4;
            int k = g * 8 + j, ch = tt * 16 + c;
            float s = g1[ch] * rsqrtf(v1[ch] + EPS);
            float val = (k < 16) ? W1[k * 64 + ch] * s
                      : (k == 16 ? b1[ch] - m1[ch] * s : 0.f);
            wsu[i] = f2bf(val);
        }
        for (int i = t; i < 4096; i += 256) {           // w2aA (A-frag)
            int mt = i >> 9, lane = (i >> 3) & 63, j = i & 7;
            int c = lane & 15, g = lane >> 4;
            int k = g * 8 + j, ch = mt * 16 + c;
            float s = g2a[ch] * rsqrtf(v2a[ch] + EPS);
            float val = (k < 16) ? W2a[k * 128 + ch] * s
                      : (k == 16 ? b2a[ch] - m2a[ch] * s : 0.f);
            wsu[2048 + i] = f2bf(val);
        }
        for (int i = t; i < 8192; i += 256) {           // w2bB (B-frag, f=ks*4+t)
            int f = i >> 9, lane = (i >> 3) & 63, j = i & 7;
            int ks = f >> 2, tt = f & 3;
            int c = lane & 15, g = lane >> 4;
            int k = ks * 32 + g * 8 + j, ch = tt * 16 + c;
            float s = g2b[ch] * rsqrtf(v2b[ch] + EPS);
            wsu[6144 + i] = f2bf(W2b[k * 64 + ch] * s);
        }
        if (t < 64) {
            float s = g2b[t] * rsqrtf(v2b[t] + EPS);
            wsf[OFF_T2B + t] = b2b[t] - m2b[t] * s;
        }
    } else {
        const int i = (blockIdx.x - 1) * 256 + t;
        if (i < N) atomicAdd(&cnt[unq[i]], 1);
    }
}

// serial-per-thread two-pass scan
__global__ __launch_bounds__(1024) void scan_k(
    const int* __restrict__ cnt, int* __restrict__ offs,
    int* __restrict__ cur, int S)
{
    __shared__ int tot[1024];
    const int t = threadIdx.x;
    const int E = (S + 1023) >> 10;
    const int i0 = t * E;
    int run = 0;
    for (int j = 0; j < E; ++j) {
        const int i = i0 + j;
        run += (i < S) ? cnt[i] : 0;
    }
    tot[t] = run;
    __syncthreads();
    for (int d = 1; d < 1024; d <<= 1) {
        int x = (t >= d) ? tot[t - d] : 0;
        __syncthreads();
        tot[t] += x;
        __syncthreads();
    }
    int base = (t == 0) ? 0 : tot[t - 1];
    for (int j = 0; j < E; ++j) {
        const int i = i0 + j;
        if (i < S) {
            offs[i] = base;
            cur[i]  = base;
            base += cnt[i];
        }
    }
    if (t == 1023) offs[S] = tot[1023];
}

// one 16-pt tile of branch 2, swapped phase C: D[pt][ch], mp[4].
// scr is 2KB/wave: phase B/C done in two mt-halves.
__device__ __forceinline__ void b2_tile(
    const U4& bf, const short8 (&w2a)[8],
    const char* __restrict__ w2bs, char* __restrict__ scr,
    float (&mp)[4], int lane, int c, int g, bool act, int pt_lim)
{
    const f32x4 zero4 = {0.f, 0.f, 0.f, 0.f};
    f32x4 y2t[4];
    #pragma unroll
    for (int tt = 0; tt < 4; ++tt) y2t[tt] = zero4;

    #pragma unroll
    for (int half = 0; half < 2; ++half) {
        __builtin_amdgcn_wave_barrier();            // scr reuse fence
        #pragma unroll
        for (int m = 0; m < 4; ++m) {
            const int mt = half * 4 + m;
            f32x4 hT = __builtin_amdgcn_mfma_f32_16x16x32_bf16(w2a[mt], bf.s8, zero4, 0, 0, 0);
            float h0 = fmaxf(hT[0], 0.f), h1 = fmaxf(hT[1], 0.f);
            float h2 = fmaxf(hT[2], 0.f), h3 = fmaxf(hT[3], 0.f);
            unsigned lo, hi;
            asm("v_cvt_pk_bf16_f32 %0, %1, %2" : "=v"(lo) : "v"(h0), "v"(h1));
            asm("v_cvt_pk_bf16_f32 %0, %1, %2" : "=v"(hi) : "v"(h2), "v"(h3));
            const int gw = 2 * (mt & 1) + (g >> 1);
            *reinterpret_cast<uint2*>(
                &scr[((mt >> 1) & 1) * 1024 + (gw * 16 + c) * 16 + (g & 1) * 8])
                = make_uint2(lo, hi);
        }
        __builtin_amdgcn_wave_barrier();
        #pragma unroll
        for (int ksl = 0; ksl < 2; ++ksl) {
            short8 hb = *reinterpret_cast<const short8*>(&scr[ksl * 1024 + lane * 16]);
            const int ks = half * 2 + ksl;
            #pragma unroll
            for (int tt = 0; tt < 4; ++tt) {
                short8 b = *reinterpret_cast<const short8*>(
                    &w2bs[((ks * 4 + tt) * 64 + lane) * 16]);
                y2t[tt] = __builtin_amdgcn_mfma_f32_16x16x32_bf16(hb, b, y2t[tt], 0, 0, 0);
            }
        }
    }
    // D[pt = g*4+r][ch = tt*16+c]; raw running max over pts (bias deferred)
    if (act) {
        #pragma unroll
        for (int tt = 0; tt < 4; ++tt)
            #pragma unroll
            for (int r = 0; r < 4; ++r)
                if (g * 4 + r < pt_lim)
                    mp[tt] = fmaxf(mp[tt], y2t[tt][r]);
    }
}

// Fused scatter + branch-2 + max-pool partials.
__global__ __launch_bounds__(256, 5) void brscat_k(
    const float* __restrict__ inputs,
    const int*   __restrict__ unq,
    int*         __restrict__ cur,
    uint4*       __restrict__ inpS,
    const uint4* __restrict__ wsw,
    const float* __restrict__ wsf,
    float* __restrict__ mpp,
    int N)
{
    __shared__ __align__(16) char w2bs[16384];      // [16 frag][64 lane][16B]
    __shared__ __align__(16) char scrs[4][2048];    // per-wave h staging (half)
    __shared__ float mpb[64];

    const int tid  = threadIdx.x;
    const int wv   = tid >> 6;
    const int lane = tid & 63;
    const int c = lane & 15;
    const int g = lane >> 4;

    #pragma unroll
    for (int u = 0; u < 4; ++u)                     // w2b -> LDS (1024 uint4)
        reinterpret_cast<uint4*>(w2bs)[u * 256 + tid] = wsw[768 + u * 256 + tid];
    if (tid < 64) mpb[tid] = 0.f;
    __syncthreads();

    short8 w2a[8];                                   // 32 VGPR
    #pragma unroll
    for (int s = 0; s < 8; ++s) {
        U4 t; t.u4 = wsw[256 + s * 64 + lane]; w2a[s] = t.s8;
    }
    #pragma unroll
    for (int s = 0; s < 8; ++s) asm volatile("" : "+v"(w2a[s]));

    char* scr = scrs[wv];
    float mp[4];
    #pragma unroll
    for (int j = 0; j < 4; ++j) mp[j] = -3.0e38f;    // bias deferred

    const unsigned loff = (unsigned)(c * 64 + g * 32);   // byte offset in chunk
    const long stride = (long)gridDim.x * 256;
    for (long base = (long)blockIdx.x * 256 + (long)wv * 64; base < N; base += stride) {
        const long nrem = (long)N - base;

        if (nrem >= 64) {
            // ---- full chunk: no masks anywhere ----
            const int pos = atomicAdd(&cur[unq[base + lane]], 1);
            const char* bp = reinterpret_cast<const char*>(inputs + base * 16);
            #pragma unroll
            for (int ti = 0; ti < 4; ++ti) {
                U4 bf;
                if (g < 2) {
                    float4 q0 = *reinterpret_cast<const float4*>(bp + loff + ti * 1024);
                    float4 q1 = *reinterpret_cast<const float4*>(bp + loff + ti * 1024 + 16);
                    asm("v_cvt_pk_bf16_f32 %0, %1, %2" : "=v"(bf.u[0]) : "v"(q0.x), "v"(q0.y));
                    asm("v_cvt_pk_bf16_f32 %0, %1, %2" : "=v"(bf.u[1]) : "v"(q0.z), "v"(q0.w));
                    asm("v_cvt_pk_bf16_f32 %0, %1, %2" : "=v"(bf.u[2]) : "v"(q1.x), "v"(q1.y));
                    asm("v_cvt_pk_bf16_f32 %0, %1, %2" : "=v"(bf.u[3]) : "v"(q1.z), "v"(q1.w));
                } else {
                    bf.u[0] = (g == 2) ? 0x00003F80u : 0u;   // k16 = 1.0 (bias)
                    bf.u[1] = 0u; bf.u[2] = 0u; bf.u[3] = 0u;
                }
                const int posc = __shfl(pos, ti * 16 + c, 64);
                if (g < 2)
                    inpS[(size_t)posc * 2 + g] = bf.u4;
                b2_tile(bf, w2a, w2bs, scr, mp, lane, c, g, true, 16);
            }
        } else {
            // ---- tail chunk: masked ----
            int pos = 0;
            if (lane < nrem) pos = atomicAdd(&cur[unq[base + lane]], 1);
            #pragma unroll
            for (int ti = 0; ti < 4; ++ti) {
                if ((long)ti * 16 >= nrem) break;
                const bool act = (long)(ti * 16 + c) < nrem;
                U4 bf;
                if (g < 2) {
                    const long row = act ? (base + ti * 16 + c) : base;
                    const float4* p = reinterpret_cast<const float4*>(inputs + row * 16 + g * 8);
                    float4 q0 = p[0], q1 = p[1];
                    asm("v_cvt_pk_bf16_f32 %0, %1, %2" : "=v"(bf.u[0]) : "v"(q0.x), "v"(q0.y));
                    asm("v_cvt_pk_bf16_f32 %0, %1, %2" : "=v"(bf.u[1]) : "v"(q0.z), "v"(q0.w));
                    asm("v_cvt_pk_bf16_f32 %0, %1, %2" : "=v"(bf.u[2]) : "v"(q1.x), "v"(q1.y));
                    asm("v_cvt_pk_bf16_f32 %0, %1, %2" : "=v"(bf.u[3]) : "v"(q1.z), "v"(q1.w));
                    if (!act) { bf.u[0] = 0u; bf.u[1] = 0u; bf.u[2] = 0u; bf.u[3] = 0u; }
                } else {
                    bf.u[0] = (g == 2 && act) ? 0x00003F80u : 0u;
                    bf.u[1] = 0u; bf.u[2] = 0u; bf.u[3] = 0u;
                }
                const int posc = __shfl(pos, ti * 16 + c, 64);
                if (g < 2 && act)
                    inpS[(size_t)posc * 2 + g] = bf.u4;
                const int pl = (int)min((long)16, nrem - (long)ti * 16);
                b2_tile(bf, w2a, w2bs, scr, mp, lane, c, g, true, pl);
            }
        }
    }

    // ---- combine pt-row groups (g), then bias+relu, block max ----
    #pragma unroll
    for (int tt = 0; tt < 4; ++tt) {
        float x = mp[tt];
        x = fmaxf(x, __shfl_xor(x, 16, 64));
        x = fmaxf(x, __shfl_xor(x, 32, 64));
        mp[tt] = x;
    }
    if (g == 0) {   // lane c holds ch = tt*16+c
        #pragma unroll
        for (int tt = 0; tt < 4; ++tt) {
            const int ch = tt * 16 + c;
            const float v = fmaxf(mp[tt] + wsf[OFF_T2B + ch], 0.f);
            atomicMax(reinterpret_cast<int*>(&mpb[ch]), __float_as_int(v));
        }
    }
    __syncthreads();
    if (tid < 64)
        atomicMax(reinterpret_cast<int*>(mpp + (blockIdx.x & 63) * 64 + tid),
                  __float_as_int(mpb[tid]));
}

// One wave per segment on SORTED bf16 inputs, grid-stride, swapped
// operands: D[pt][ch] -> reduce = 3 in-lane ops + 2 shfl per quantity.
__global__ __launch_bounds__(256, 6) void seg1_k(
    const uint4* __restrict__ inpS,
    const int*   __restrict__ offs,
    const uint4* __restrict__ wsw,
    const float* __restrict__ mpp,
    float* __restrict__ out,
    int S)
{
    __shared__ float scr3[4][192];

    const int tid  = threadIdx.x;
    const int wv   = tid >> 6;
    const int lane = tid & 63;
    const int c = lane & 15;
    const int g = lane >> 4;

    short8 w1[4];                                 // B-frags (16 VGPR), L2-hot
    #pragma unroll
    for (int tt = 0; tt < 4; ++tt) {
        U4 t; t.u4 = wsw[tt * 64 + lane]; w1[tt] = t.s8;
    }
    float mpl = 0.f;                               // finalize max-pool per wave
    #pragma unroll
    for (int s = 0; s < 64; ++s)
        mpl = fmaxf(mpl, mpp[s * 64 + lane]);

    float* sr = scr3[wv];
    const f32x4 zero4 = {0.f, 0.f, 0.f, 0.f};

    const int nw = gridDim.x * 4;
    for (int seg = blockIdx.x * 4 + wv; seg < S; seg += nw) {
        const int su    = __builtin_amdgcn_readfirstlane(seg);
        const int start = offs[su];
        const int end   = offs[su + 1];

        float as[4], am[4];
        #pragma unroll
        for (int tt = 0; tt < 4; ++tt) { as[tt] = 0.f; am[tt] = 0.f; }

        for (int base = start; base < end; base += 64) {
            const int nrem = end - base;
            #pragma unroll
            for (int ti = 0; ti < 4; ++ti) {
                if (ti * 16 >= nrem) break;                 // wave-uniform
                const bool act = (ti * 16 + c) < nrem;

                U4 bf;                                       // A-frag: in[pt=c][k]
                if (g < 2) {
                    const int row = act ? (base + ti * 16 + c) : start;
                    uint4 q = inpS[(size_t)row * 2 + g];
                    bf.u[0] = act ? q.x : 0u;
                    bf.u[1] = act ? q.y : 0u;
                    bf.u[2] = act ? q.z : 0u;
                    bf.u[3] = act ? q.w : 0u;
                } else {
                    bf.u[0] = (g == 2 && act) ? 0x00003F80u : 0u;
                    bf.u[1] = 0u; bf.u[2] = 0u; bf.u[3] = 0u;
                }
                #pragma unroll
                for (int tt = 0; tt < 4; ++tt) {
                    f32x4 y1t = __builtin_amdgcn_mfma_f32_16x16x32_bf16(bf.s8, w1[tt], zero4, 0, 0, 0);
                    #pragma unroll
                    for (int r = 0; r < 4; ++r) {
                        float v = fmaxf(y1t[r], 0.f);   // inactive rows give 0
                        as[tt] += v;
                        am[tt]  = fmaxf(am[tt], v);
                    }
                }
            }
        }

        // ---- combine pt-row groups (g): 2 shfl per quantity ----
        #pragma unroll
        for (int tt = 0; tt < 4; ++tt) {
            float xs = as[tt], xm = am[tt];
            xs += __shfl_xor(xs, 16, 64);  xm = fmaxf(xm, __shfl_xor(xm, 16, 64));
            xs += __shfl_xor(xs, 32, 64);  xm = fmaxf(xm, __shfl_xor(xm, 32, 64));
            as[tt] = xs; am[tt] = xm;
        }

        // ---- stage channel-shuffled 192 floats, 3 coalesced line writes ----
        if (g == 0) {   // lane c holds ch = tt*16 + c
            #pragma unroll
            for (int tt = 0; tt < 4; ++tt) {
                const int ch = tt * 16 + c;
                sr[ch * 3 + 0] = as[tt];
                sr[ch * 3 + 1] = am[tt];
            }
        }
        sr[lane * 3 + 2] = mpl;
        __builtin_amdgcn_wave_barrier();
        asm volatile("s_waitcnt lgkmcnt(0)" ::: "memory");
        __builtin_amdgcn_sched_barrier(0);

        float* o = out + (size_t)seg * 192;
        #pragma unroll
        for (int p = 0; p < 3; ++p)
            o[p * 64 + lane] = sr[p * 64 + lane];
        __builtin_amdgcn_wave_barrier();
    }
}

extern "C" void kernel_launch(void* const* d_in, const int* in_sizes, int n_in,
                              void* d_out, int out_size, void* d_ws, size_t ws_size,
                              hipStream_t stream)
{
    const float* inputs = (const float*)d_in[0];
    const int*   unq    = (const int*)d_in[1];
    const float* W1  = (const float*)d_in[3];
    const float* g1  = (const float*)d_in[4];
    const float* b1  = (const float*)d_in[5];
    const float* m1  = (const float*)d_in[6];
    const float* v1  = (const float*)d_in[7];
    const float* W2a = (const float*)d_in[8];
    const float* g2a = (const float*)d_in[9];
    const float* b2a = (const float*)d_in[10];
    const float* m2a = (const float*)d_in[11];
    const float* v2a = (const float*)d_in[12];
    const float* W2b = (const float*)d_in[13];
    const float* g2b = (const float*)d_in[14];
    const float* b2b = (const float*)d_in[15];
    const float* m2b = (const float*)d_in[16];
    const float* v2b = (const float*)d_in[17];

    float* wsf = (float*)d_ws;
    float* out = (float*)d_out;
    const int N = in_sizes[0] / 16;
    const int S = out_size / 192;

    float* mpp  = wsf + OFF_MPP;
    int*   cnt  = (int*)(wsf + OFF_CNT);
    int*   offs = (int*)(wsf + OFF_OFFS);
    int*   cur  = (int*)(wsf + OFF_CUR);
    uint4* inpS = (uint4*)(wsf + OFF_INPS);

    // zero mpp + cnt (contiguous region)
    hipMemsetAsync(mpp, 0, (size_t)(OFF_CNT + 20016 - OFF_MPP) * sizeof(float), stream);

    init_k<<<1 + (N + 255) / 256, 256, 0, stream>>>(
        W1, g1, b1, m1, v1, W2a, g2a, b2a, m2a, v2a, W2b, g2b, b2b, m2b, v2b,
        (unsigned short*)d_ws, wsf, unq, cnt, N);

    scan_k<<<1, 1024, 0, stream>>>(cnt, offs, cur, S);

    brscat_k<<<2048, 256, 0, stream>>>(inputs, unq, cur, inpS,
                                       (const uint4*)d_ws, wsf, mpp, N);

    seg1_k<<<2048, 256, 0, stream>>>(inpS, offs, (const uint4*)d_ws,
                                     mpp, out, S);
}